// Round 6
// baseline (538.743 us; speedup 1.0000x reference)
//
#include <hip/hip_runtime.h>
#include <stdint.h>

#define NROWS 131072
#define DIM 256

typedef __attribute__((ext_vector_type(4))) float f32x4;
typedef __attribute__((ext_vector_type(8))) float f32x8;
typedef __attribute__((ext_vector_type(8))) __bf16 bf16x8;
typedef __attribute__((ext_vector_type(8))) short s16x8;

// exact f32 -> bf16 truncation: valid when the value is exactly representable
// in bf16 (integers |v| <= 255, or +-1): low 16 mantissa bits are zero.
__device__ __forceinline__ short bftrunc(float f) {
  return (short)(__float_as_uint(f) >> 16);
}

// ---------------- LN stats + global absmax of xn, for the raw input x ----------------
__global__ __launch_bounds__(256) void k_stats(const float* __restrict__ x,
                                               float* __restrict__ mu_o, float* __restrict__ rs_o,
                                               unsigned* __restrict__ gslot) {
  const int l = threadIdx.x & 63;
  const int gw = blockIdx.x * 4 + (threadIdx.x >> 6);  // 8192 waves
  float gmax = 0.f;
  for (int i = 0; i < 16; ++i) {
    const int row = gw * 16 + i;
    f32x4 v = *(const f32x4*)(x + (size_t)row * DIM + l * 4);
    float s = v.x + v.y + v.z + v.w;
    #pragma unroll
    for (int m = 1; m < 64; m <<= 1) s += __shfl_xor(s, m);
    const float mu = s * (1.f / 256.f);
    float d0 = v.x - mu, d1 = v.y - mu, d2 = v.z - mu, d3 = v.w - mu;
    float sq = d0 * d0 + d1 * d1 + d2 * d2 + d3 * d3;
    float am = fmaxf(fmaxf(fabsf(d0), fabsf(d1)), fmaxf(fabsf(d2), fabsf(d3)));
    #pragma unroll
    for (int m = 1; m < 64; m <<= 1) {
      sq += __shfl_xor(sq, m);
      am = fmaxf(am, __shfl_xor(am, m));
    }
    const float rstd = rsqrtf(sq * (1.f / 256.f) + 1e-5f);
    if (l == 0) { mu_o[row] = mu; rs_o[row] = rstd; }
    gmax = fmaxf(gmax, am * rstd);
  }
  if (l == 0) atomicMax(gslot + (gw & 63), __float_as_uint(gmax));
}

// ---------------- weight alpha/beta: stage 1 (64 blocks x 3 layers) ----------------
__global__ __launch_bounds__(256) void k_wstats1(const float* __restrict__ W0,
                                                 const float* __restrict__ W1,
                                                 const float* __restrict__ W2,
                                                 float2* __restrict__ part) {
  const int layer = blockIdx.y;
  const float* W = layer == 0 ? W0 : (layer == 1 ? W1 : W2);
  const int idx = (blockIdx.x * 256 + threadIdx.x) * 4;
  f32x4 v = *(const f32x4*)(W + idx);
  float s = v.x + v.y + v.z + v.w;
  float sa = fabsf(v.x) + fabsf(v.y) + fabsf(v.z) + fabsf(v.w);
  #pragma unroll
  for (int m = 1; m < 64; m <<= 1) { s += __shfl_xor(s, m); sa += __shfl_xor(sa, m); }
  __shared__ float bs[4], ba[4];
  const int w = threadIdx.x >> 6, l = threadIdx.x & 63;
  if (l == 0) { bs[w] = s; ba[w] = sa; }
  __syncthreads();
  if (threadIdx.x == 0) {
    float2 p;
    p.x = bs[0] + bs[1] + bs[2] + bs[3];
    p.y = ba[0] + ba[1] + ba[2] + ba[3];
    part[layer * 64 + blockIdx.x] = p;
  }
}

// ---------------- weight alpha/beta: stage 2 (3 blocks x 64 threads) ----------------
__global__ __launch_bounds__(64) void k_wstats2(const float2* __restrict__ part,
                                                float* __restrict__ ab) {
  const int layer = blockIdx.x;
  float2 p = part[layer * 64 + threadIdx.x];
  float s = p.x, sa = p.y;
  #pragma unroll
  for (int m = 1; m < 64; m <<= 1) { s += __shfl_xor(s, m); sa += __shfl_xor(sa, m); }
  if (threadIdx.x == 0) {
    ab[layer] = s * (1.f / 65536.f);
    ab[3 + layer] = fmaxf(sa * (1.f / 65536.f), 1e-8f);
  }
}

// ---------------- pack wb = sign(W - alpha) into MFMA B-fragment order ----------------
// packed bf16 index p = ((kt*16 + nt)*64 + lane)*8 + r  ->  B[k][j], k = kt*32 + 8*(lane>>4) + r,
// j = nt*16 + (lane&15), B[k][j] = sign(W[j][k] - alpha)
__global__ __launch_bounds__(256) void k_pack(const float* __restrict__ W0,
                                              const float* __restrict__ W1,
                                              const float* __restrict__ W2,
                                              const float* __restrict__ ab,
                                              unsigned short* __restrict__ bp) {
  const int layer = blockIdx.y;
  const float* W = layer == 0 ? W0 : (layer == 1 ? W1 : W2);
  const float alpha = ab[layer];
  const int p = blockIdx.x * 256 + threadIdx.x;  // 0..65535
  const int r = p & 7, l = (p >> 3) & 63, nt = (p >> 9) & 15, kt = p >> 13;
  const int k = kt * 32 + ((l >> 4) << 3) + r;
  const int j = nt * 16 + (l & 15);
  const float wv = W[j * 256 + k] - alpha;   // exact reference order
  bp[layer * 65536 + p] = (wv > 0.f) ? 0x3F80u : 0xBF80u;  // +1 / -1 bf16
}

// ---------------- fused quant + GEMM + scale (+relu + next-layer LN stats) ----------------
// Barrier-free, LDS-free: block = 4 independent waves; wave = 32 rows x 256 cols.
// A is quantized register-direct (lane loads exactly its fragment's 8 f32 per chunk);
// B fragments are read straight from global (128 KB panel, L2-resident).
// K=256 as 8 chunks of 32. Grid: 1024 blocks x 128 rows.
// NOTE: src and bout may ALIAS (layer 3 reads h2 from d_out, writes out in place).
// Safe: each wave reads only its own 32 rows, all reads precede its epilogue writes.
template <int FINAL>
__global__ __launch_bounds__(256, 2) void k_gemm(
    const float* src, const float* __restrict__ mu, const float* __restrict__ rs,
    const unsigned* __restrict__ gslot, const unsigned short* __restrict__ bp,
    const float* __restrict__ beta_p,
    float* __restrict__ hout, float* bout,
    float* __restrict__ mu_n, float* __restrict__ rs_n, unsigned* __restrict__ gslot_n) {
  const int t = threadIdx.x, l = t & 63, w = t >> 6;
  const int row0 = blockIdx.x * 128 + w * 32;   // this wave's 32-row window
  const int lr = l & 15, g2 = l >> 4;

  // gamma: wave-local butterfly over the 64 atomic slots
  float gm = __uint_as_float(gslot[l]);
  #pragma unroll
  for (int m = 1; m < 64; m <<= 1) gm = fmaxf(gm, __shfl_xor(gm, m));
  const float gamma = fmaxf(gm, 1e-8f);
  const float qs = 127.f / gamma;
  const float beta = *beta_p;
  const float oscale = beta * gamma * (1.f / 127.f);

  // per-lane LN constants for the two 16-row tiles this lane's A-fragments cover
  const float mu0 = mu[row0 + lr],      rs0 = rs[row0 + lr];
  const float mu1 = mu[row0 + 16 + lr], rs1 = rs[row0 + 16 + lr];

  f32x4 acc[2][16];
  #pragma unroll
  for (int mt = 0; mt < 2; ++mt)
    #pragma unroll
    for (int i = 0; i < 16; ++i) acc[mt][i] = (f32x4){0.f, 0.f, 0.f, 0.f};

  const float* a0p = src + (size_t)(row0 + lr) * DIM + g2 * 8;
  const float* a1p = a0p + 16 * DIM;
  const unsigned short* bpl = bp + l * 8;

  #pragma unroll
  for (int c = 0; c < 8; ++c) {           // k32-chunk
    f32x8 v0 = *(const f32x8*)(a0p + c * 32);
    f32x8 v1 = *(const f32x8*)(a1p + c * 32);
    union { s16x8 s; bf16x8 b; } a0u, a1u;
    #pragma unroll
    for (int e = 0; e < 8; ++e) {
      float xn = (v0[e] - mu0) * rs0;     // exact reference order
      float xs = xn * qs;
      xs = fminf(fmaxf(xs, -127.f), 127.f);
      a0u.s[e] = bftrunc(rintf(xs));
      float yn = (v1[e] - mu1) * rs1;
      float ys = yn * qs;
      ys = fminf(fmaxf(ys, -127.f), 127.f);
      a1u.s[e] = bftrunc(rintf(ys));
    }
    #pragma unroll
    for (int nt = 0; nt < 16; ++nt) {
      bf16x8 b = *(const bf16x8*)(bpl + (c * 16 + nt) * 512);
      acc[0][nt] = __builtin_amdgcn_mfma_f32_16x16x32_bf16(a0u.b, b, acc[0][nt], 0, 0, 0);
      acc[1][nt] = __builtin_amdgcn_mfma_f32_16x16x32_bf16(a1u.b, b, acc[1][nt], 0, 0, 0);
    }
  }

  // epilogue: C/D layout (m89-verified): col = lane&15, row-in-tile = (lane>>4)*4 + reg
  if constexpr (FINAL == 1) {
    #pragma unroll
    for (int mt = 0; mt < 2; ++mt)
      #pragma unroll
      for (int nt = 0; nt < 16; ++nt)
        #pragma unroll
        for (int rr = 0; rr < 4; ++rr) {
          const int grow = row0 + mt * 16 + g2 * 4 + rr;
          bout[(size_t)grow * DIM + nt * 16 + lr] = acc[mt][nt][rr] * oscale;
        }
  } else {
    float gmax = 0.f;
    #pragma unroll
    for (int mt = 0; mt < 2; ++mt) {
      float sum[4] = {0.f, 0.f, 0.f, 0.f};
      #pragma unroll
      for (int nt = 0; nt < 16; ++nt)
        #pragma unroll
        for (int rr = 0; rr < 4; ++rr) {
          float h = fmaxf(acc[mt][nt][rr] * oscale, 0.f);
          acc[mt][nt][rr] = h;
          sum[rr] += h;
          hout[(size_t)(row0 + mt * 16 + g2 * 4 + rr) * DIM + nt * 16 + lr] = h;
        }
      #pragma unroll
      for (int rr = 0; rr < 4; ++rr) {
        float s_ = sum[rr];
        s_ += __shfl_xor(s_, 1); s_ += __shfl_xor(s_, 2);
        s_ += __shfl_xor(s_, 4); s_ += __shfl_xor(s_, 8);
        const float m_ = s_ * (1.f / 256.f);
        float sq = 0.f, am = 0.f;
        #pragma unroll
        for (int nt = 0; nt < 16; ++nt) {
          float d = acc[mt][nt][rr] - m_;
          sq += d * d;
          am = fmaxf(am, fabsf(d));
        }
        sq += __shfl_xor(sq, 1); sq += __shfl_xor(sq, 2);
        sq += __shfl_xor(sq, 4); sq += __shfl_xor(sq, 8);
        am = fmaxf(am, __shfl_xor(am, 1)); am = fmaxf(am, __shfl_xor(am, 2));
        am = fmaxf(am, __shfl_xor(am, 4)); am = fmaxf(am, __shfl_xor(am, 8));
        const float rstd = rsqrtf(sq * (1.f / 256.f) + 1e-5f);
        const int grow = row0 + mt * 16 + g2 * 4 + rr;
        if (lr == 0) { mu_n[grow] = m_; rs_n[grow] = rstd; }
        gmax = fmaxf(gmax, am * rstd);
      }
    }
    gmax = fmaxf(gmax, __shfl_xor(gmax, 16));
    gmax = fmaxf(gmax, __shfl_xor(gmax, 32));
    if (l == 0) atomicMax(gslot_n + (blockIdx.x & 63), __float_as_uint(gmax));
  }
}

extern "C" void kernel_launch(void* const* d_in, const int* in_sizes, int n_in,
                              void* d_out, int out_size, void* d_ws, size_t ws_size,
                              hipStream_t stream) {
  const float* x  = (const float*)d_in[0];
  const float* W1 = (const float*)d_in[1];
  const float* W2 = (const float*)d_in[2];
  const float* W3 = (const float*)d_in[3];

  char* ws = (char*)d_ws;
  unsigned* gslot = (unsigned*)ws;                      // [3][64] u32
  float* ab = (float*)(ws + 1024);                      // alpha[3], beta[3]
  float2* part = (float2*)(ws + 2048);                  // [3][64] float2 partials
  float* muv = (float*)(ws + 4096);                     // [3][131072] f32
  float* rsv = (float*)(ws + 4096 + 3 * 524288);        // [3][131072] f32
  unsigned short* bp = (unsigned short*)(ws + 3149824); // [3][65536] bf16
  float* h1 = (float*)(ws + 4194304);                   // [131072][256] f32
  float* h2 = (float*)d_out;                            // reuse output buffer for h2

  hipMemsetAsync(gslot, 0, 768, stream);
  dim3 wg(64, 3);
  k_wstats1<<<wg, 256, 0, stream>>>(W1, W2, W3, part);
  k_wstats2<<<3, 64, 0, stream>>>(part, ab);
  dim3 pg(256, 3);
  k_pack<<<pg, 256, 0, stream>>>(W1, W2, W3, ab, bp);
  k_stats<<<2048, 256, 0, stream>>>(x, muv, rsv, gslot);

  k_gemm<0><<<1024, 256, 0, stream>>>(x, muv, rsv, gslot, bp, ab + 3,
                                      h1, nullptr,
                                      muv + 131072, rsv + 131072, gslot + 64);
  k_gemm<0><<<1024, 256, 0, stream>>>(h1, muv + 131072, rsv + 131072, gslot + 64,
                                      bp + 65536, ab + 4,
                                      h2, nullptr,
                                      muv + 262144, rsv + 262144, gslot + 128);
  k_gemm<1><<<1024, 256, 0, stream>>>(h2, muv + 262144, rsv + 262144, gslot + 128,
                                      bp + 131072, ab + 5,
                                      nullptr, (float*)d_out,
                                      nullptr, nullptr, nullptr);
}

// Round 7
// 444.048 us; speedup vs baseline: 1.2133x; 1.2133x over previous
//
#include <hip/hip_runtime.h>
#include <stdint.h>

#define NROWS 131072
#define DIM 256

typedef __attribute__((ext_vector_type(4))) float f32x4;
typedef __attribute__((ext_vector_type(8))) __bf16 bf16x8;
typedef __attribute__((ext_vector_type(8))) short s16x8;

// exact f32 -> bf16 truncation: valid when value is exactly representable (ints <=255)
__device__ __forceinline__ short bftrunc(float f) {
  return (short)(__float_as_uint(f) >> 16);
}

__device__ __forceinline__ short quant1(float v, float mu_, float rs_, float qs) {
  float xn = (v - mu_) * rs_;        // exact reference order
  float xs = xn * qs;
  xs = fminf(fmaxf(xs, -127.f), 127.f);
  return bftrunc(rintf(xs));
}

__device__ __forceinline__ void gload_lds16(const void* g, void* lds) {
  __builtin_amdgcn_global_load_lds((const __attribute__((address_space(1))) void*)g,
                                   (__attribute__((address_space(3))) void*)lds, 16, 0, 0);
}

// ---------------- LN stats + global absmax of xn, for the raw input x ----------------
__global__ __launch_bounds__(256) void k_stats(const float* __restrict__ x,
                                               float* __restrict__ mu_o, float* __restrict__ rs_o,
                                               unsigned* __restrict__ gslot) {
  const int l = threadIdx.x & 63;
  const int gw = blockIdx.x * 4 + (threadIdx.x >> 6);  // 8192 waves
  float gmax = 0.f;
  for (int i = 0; i < 16; ++i) {
    const int row = gw * 16 + i;
    f32x4 v = *(const f32x4*)(x + (size_t)row * DIM + l * 4);
    float s = v.x + v.y + v.z + v.w;
    #pragma unroll
    for (int m = 1; m < 64; m <<= 1) s += __shfl_xor(s, m);
    const float mu = s * (1.f / 256.f);
    float d0 = v.x - mu, d1 = v.y - mu, d2 = v.z - mu, d3 = v.w - mu;
    float sq = d0 * d0 + d1 * d1 + d2 * d2 + d3 * d3;
    float am = fmaxf(fmaxf(fabsf(d0), fabsf(d1)), fmaxf(fabsf(d2), fabsf(d3)));
    #pragma unroll
    for (int m = 1; m < 64; m <<= 1) {
      sq += __shfl_xor(sq, m);
      am = fmaxf(am, __shfl_xor(am, m));
    }
    const float rstd = rsqrtf(sq * (1.f / 256.f) + 1e-5f);
    if (l == 0) { mu_o[row] = mu; rs_o[row] = rstd; }
    gmax = fmaxf(gmax, am * rstd);
  }
  if (l == 0) atomicMax(gslot + (gw & 63), __float_as_uint(gmax));
}

// ---------------- weight alpha/beta: stage 1 (64 blocks x 3 layers) ----------------
__global__ __launch_bounds__(256) void k_wstats1(const float* __restrict__ W0,
                                                 const float* __restrict__ W1,
                                                 const float* __restrict__ W2,
                                                 float2* __restrict__ part) {
  const int layer = blockIdx.y;
  const float* W = layer == 0 ? W0 : (layer == 1 ? W1 : W2);
  const int idx = (blockIdx.x * 256 + threadIdx.x) * 4;
  f32x4 v = *(const f32x4*)(W + idx);
  float s = v.x + v.y + v.z + v.w;
  float sa = fabsf(v.x) + fabsf(v.y) + fabsf(v.z) + fabsf(v.w);
  #pragma unroll
  for (int m = 1; m < 64; m <<= 1) { s += __shfl_xor(s, m); sa += __shfl_xor(sa, m); }
  __shared__ float bs[4], ba[4];
  const int w = threadIdx.x >> 6, l = threadIdx.x & 63;
  if (l == 0) { bs[w] = s; ba[w] = sa; }
  __syncthreads();
  if (threadIdx.x == 0) {
    float2 p;
    p.x = bs[0] + bs[1] + bs[2] + bs[3];
    p.y = ba[0] + ba[1] + ba[2] + ba[3];
    part[layer * 64 + blockIdx.x] = p;
  }
}

// ---------------- weight alpha/beta: stage 2 (3 blocks x 64 threads) ----------------
__global__ __launch_bounds__(64) void k_wstats2(const float2* __restrict__ part,
                                                float* __restrict__ ab) {
  const int layer = blockIdx.x;
  float2 p = part[layer * 64 + threadIdx.x];
  float s = p.x, sa = p.y;
  #pragma unroll
  for (int m = 1; m < 64; m <<= 1) { s += __shfl_xor(s, m); sa += __shfl_xor(sa, m); }
  if (threadIdx.x == 0) {
    ab[layer] = s * (1.f / 65536.f);
    ab[3 + layer] = fmaxf(sa * (1.f / 65536.f), 1e-8f);
  }
}

// ---------------- pack wb = sign(W - alpha) into MFMA B-fragment order ----------------
// packed bf16 index p = ((kt*16 + nt)*64 + lane)*8 + r  ->  B[k][j], k = kt*32 + 8*(lane>>4) + r,
// j = nt*16 + (lane&15), B[k][j] = sign(W[j][k] - alpha)
__global__ __launch_bounds__(256) void k_pack(const float* __restrict__ W0,
                                              const float* __restrict__ W1,
                                              const float* __restrict__ W2,
                                              const float* __restrict__ ab,
                                              unsigned short* __restrict__ bp) {
  const int layer = blockIdx.y;
  const float* W = layer == 0 ? W0 : (layer == 1 ? W1 : W2);
  const float alpha = ab[layer];
  const int p = blockIdx.x * 256 + threadIdx.x;  // 0..65535
  const int r = p & 7, l = (p >> 3) & 63, nt = (p >> 9) & 15, kt = p >> 13;
  const int k = kt * 32 + ((l >> 4) << 3) + r;
  const int j = nt * 16 + (l & 15);
  const float wv = W[j * 256 + k] - alpha;   // exact reference order
  bp[layer * 65536 + p] = (wv > 0.f) ? 0x3F80u : 0xBF80u;  // +1 / -1 bf16
}

// ---------------- fused quant + GEMM + scale (+relu + next-layer LN stats) ----------------
// block 256 thr = 4 waves; tile 64 rows x 256 cols; wave = 32 rows x 128 cols
// (wr = w>>1 row-half, wc = w&1 col-half). K=256 in 4 steps of 64.
// A staged as RAW f32 via global_load_lds with XOR-swizzled source (LDS dest linear);
// quant happens at fragment-read time. B staged linear via global_load_lds.
// Epilogue: LN stats across the two col-half waves via 1KB LDS exchange,
// var = E[h^2] - mu^2. gamma needs only global max -> partial atomicMax.
// NOTE: src and bout may ALIAS (layer 3). Safe: block reads only its own 64 rows,
// all staging reads precede its epilogue writes.
template <int FINAL>
__global__ __launch_bounds__(256, 3) void k_gemm(
    const float* src, const float* __restrict__ mu, const float* __restrict__ rs,
    const unsigned* __restrict__ gslot, const unsigned short* __restrict__ bp,
    const float* __restrict__ beta_p,
    float* __restrict__ hout, float* bout,
    float* __restrict__ mu_n, float* __restrict__ rs_n, unsigned* __restrict__ gslot_n) {
  __shared__ float Af[4096];             // 64 rows x 64 k f32, 16 KB, source-swizzled
  __shared__ unsigned short Bb[16384];   // 32 KB fragment-packed B chunk
  __shared__ float sS[2][64], sQ[2][64]; // col-half partial sums, 1 KB

  const int t = threadIdx.x, l = t & 63, w = t >> 6;
  const int lr = l & 15, g2 = l >> 4;
  const int wr = w >> 1, wc = w & 1;
  const int row0 = blockIdx.x * 64;

  // gamma: wave-local butterfly over the 64 atomic slots
  float gm = __uint_as_float(gslot[l]);
  #pragma unroll
  for (int m = 1; m < 64; m <<= 1) gm = fmaxf(gm, __shfl_xor(gm, m));
  const float gamma = fmaxf(gm, 1e-8f);
  const float qs = 127.f / gamma;
  const float beta = *beta_p;
  const float oscale = beta * gamma * (1.f / 127.f);

  // per-lane LN constants for this lane's two A rows (mt = 0/1)
  const int arow = wr * 32 + lr;
  const float mu0 = mu[row0 + arow],      rs0 = rs[row0 + arow];
  const float mu1 = mu[row0 + arow + 16], rs1 = rs[row0 + arow + 16];

  f32x4 acc[2][8];
  #pragma unroll
  for (int mt = 0; mt < 2; ++mt)
    #pragma unroll
    for (int i = 0; i < 8; ++i) acc[mt][i] = (f32x4){0.f, 0.f, 0.f, 0.f};

  for (int s = 0; s < 4; ++s) {
    // stage A: 16 KB raw f32, source swizzled so LDS-linear layout is bank-spread
    #pragma unroll
    for (int it = 0; it < 4; ++it) {
      const int d = w * 4096 + it * 1024 + l * 16;   // LDS byte (linear dest)
      const int row = d >> 8;                        // block-local row
      const int soff = (d & 255) ^ ((row & 7) << 4); // swizzled byte-in-row
      gload_lds16(src + (size_t)(row0 + row) * DIM + s * 64 + (soff >> 2),
                  (char*)Af + d);
    }
    // stage B: 32 KB linear copy of packed fragments
    #pragma unroll
    for (int it = 0; it < 8; ++it) {
      const int d = w * 8192 + it * 1024 + l * 16;
      gload_lds16(bp + s * 16384 + (d >> 1), (char*)Bb + d);
    }
    __syncthreads();

    #pragma unroll
    for (int kt2 = 0; kt2 < 2; ++kt2) {
      // build A fragments: swizzled ds_read + quant
      bf16x8 af[2];
      #pragma unroll
      for (int mt = 0; mt < 2; ++mt) {
        const int row = wr * 32 + mt * 16 + lr;
        const int base = row * 256 + kt2 * 128 + g2 * 32;
        const int sw = (lr & 7) << 4;
        f32x4 v0 = *(const f32x4*)((const char*)Af + (base ^ sw));
        f32x4 v1 = *(const f32x4*)((const char*)Af + ((base + 16) ^ sw));
        const float mu_ = mt ? mu1 : mu0;
        const float rs_ = mt ? rs1 : rs0;
        union { s16x8 sv; bf16x8 bv; } u;
        #pragma unroll
        for (int e = 0; e < 4; ++e) {
          u.sv[e]     = quant1(v0[e], mu_, rs_, qs);
          u.sv[e + 4] = quant1(v1[e], mu_, rs_, qs);
        }
        af[mt] = u.bv;
      }
      #pragma unroll
      for (int nt = 0; nt < 8; ++nt) {
        const int ntg = wc * 8 + nt;
        bf16x8 b = *(const bf16x8*)&Bb[((kt2 * 16 + ntg) * 64 + l) * 8];
        acc[0][nt] = __builtin_amdgcn_mfma_f32_16x16x32_bf16(af[0], b, acc[0][nt], 0, 0, 0);
        acc[1][nt] = __builtin_amdgcn_mfma_f32_16x16x32_bf16(af[1], b, acc[1][nt], 0, 0, 0);
      }
    }
    __syncthreads();
  }

  // epilogue: C/D layout (m89-verified): col-in-tile = lane&15, row-in-tile = (lane>>4)*4 + reg
  if constexpr (FINAL == 1) {
    #pragma unroll
    for (int mt = 0; mt < 2; ++mt)
      #pragma unroll
      for (int nt = 0; nt < 8; ++nt)
        #pragma unroll
        for (int rr = 0; rr < 4; ++rr) {
          const int grow = row0 + wr * 32 + mt * 16 + g2 * 4 + rr;
          bout[(size_t)grow * DIM + (wc * 8 + nt) * 16 + lr] = acc[mt][nt][rr] * oscale;
        }
  } else {
    float ps[2][4], pq[2][4];
    #pragma unroll
    for (int mt = 0; mt < 2; ++mt) {
      #pragma unroll
      for (int rr = 0; rr < 4; ++rr) { ps[mt][rr] = 0.f; pq[mt][rr] = 0.f; }
      #pragma unroll
      for (int nt = 0; nt < 8; ++nt)
        #pragma unroll
        for (int rr = 0; rr < 4; ++rr) {
          float h = fmaxf(acc[mt][nt][rr] * oscale, 0.f);
          acc[mt][nt][rr] = h;
          ps[mt][rr] += h;
          pq[mt][rr] += h * h;
          hout[(size_t)(row0 + wr * 32 + mt * 16 + g2 * 4 + rr) * DIM + (wc * 8 + nt) * 16 + lr] = h;
        }
      #pragma unroll
      for (int rr = 0; rr < 4; ++rr) {
        #pragma unroll
        for (int m = 1; m < 16; m <<= 1) {
          ps[mt][rr] += __shfl_xor(ps[mt][rr], m);
          pq[mt][rr] += __shfl_xor(pq[mt][rr], m);
        }
      }
    }
    if (lr == 0) {
      #pragma unroll
      for (int mt = 0; mt < 2; ++mt)
        #pragma unroll
        for (int rr = 0; rr < 4; ++rr) {
          const int row_l = wr * 32 + mt * 16 + g2 * 4 + rr;
          sS[wc][row_l] = ps[mt][rr];
          sQ[wc][row_l] = pq[mt][rr];
        }
    }
    __syncthreads();
    float gmax = 0.f;
    #pragma unroll
    for (int mt = 0; mt < 2; ++mt)
      #pragma unroll
      for (int rr = 0; rr < 4; ++rr) {
        const int row_l = wr * 32 + mt * 16 + g2 * 4 + rr;
        const float s_all = sS[0][row_l] + sS[1][row_l];
        const float q_all = sQ[0][row_l] + sQ[1][row_l];
        const float m_ = s_all * (1.f / 256.f);
        const float var = q_all * (1.f / 256.f) - m_ * m_;
        const float rstd = rsqrtf(var + 1e-5f);
        if (wc == 0 && lr == 0) {
          mu_n[row0 + row_l] = m_;
          rs_n[row0 + row_l] = rstd;
        }
        float am = 0.f;
        #pragma unroll
        for (int nt = 0; nt < 8; ++nt) am = fmaxf(am, fabsf(acc[mt][nt][rr] - m_));
        gmax = fmaxf(gmax, am * rstd);
      }
    #pragma unroll
    for (int m = 1; m < 64; m <<= 1) gmax = fmaxf(gmax, __shfl_xor(gmax, m));
    if (l == 0) atomicMax(gslot_n + (blockIdx.x & 63), __float_as_uint(gmax));
  }
}

extern "C" void kernel_launch(void* const* d_in, const int* in_sizes, int n_in,
                              void* d_out, int out_size, void* d_ws, size_t ws_size,
                              hipStream_t stream) {
  const float* x  = (const float*)d_in[0];
  const float* W1 = (const float*)d_in[1];
  const float* W2 = (const float*)d_in[2];
  const float* W3 = (const float*)d_in[3];

  char* ws = (char*)d_ws;
  unsigned* gslot = (unsigned*)ws;                      // [3][64] u32
  float* ab = (float*)(ws + 1024);                      // alpha[3], beta[3]
  float2* part = (float2*)(ws + 2048);                  // [3][64] float2 partials
  float* muv = (float*)(ws + 4096);                     // [3][131072] f32
  float* rsv = (float*)(ws + 4096 + 3 * 524288);        // [3][131072] f32
  unsigned short* bp = (unsigned short*)(ws + 3149824); // [3][65536] bf16
  float* h1 = (float*)(ws + 4194304);                   // [131072][256] f32
  float* h2 = (float*)d_out;                            // reuse output buffer for h2

  hipMemsetAsync(gslot, 0, 768, stream);
  dim3 wg(64, 3);
  k_wstats1<<<wg, 256, 0, stream>>>(W1, W2, W3, part);
  k_wstats2<<<3, 64, 0, stream>>>(part, ab);
  dim3 pg(256, 3);
  k_pack<<<pg, 256, 0, stream>>>(W1, W2, W3, ab, bp);
  k_stats<<<2048, 256, 0, stream>>>(x, muv, rsv, gslot);

  k_gemm<0><<<2048, 256, 0, stream>>>(x, muv, rsv, gslot, bp, ab + 3,
                                      h1, nullptr,
                                      muv + 131072, rsv + 131072, gslot + 64);
  k_gemm<0><<<2048, 256, 0, stream>>>(h1, muv + 131072, rsv + 131072, gslot + 64,
                                      bp + 65536, ab + 4,
                                      h2, nullptr,
                                      muv + 262144, rsv + 262144, gslot + 128);
  k_gemm<1><<<2048, 256, 0, stream>>>(h2, muv + 262144, rsv + 262144, gslot + 128,
                                      bp + 131072, ab + 5,
                                      nullptr, (float*)d_out,
                                      nullptr, nullptr, nullptr);
}